// Round 3
// baseline (587.779 us; speedup 1.0000x reference)
//
#include <hip/hip_runtime.h>
#include <cstdint>
#include <cstddef>

#define MM 65536
#define NN 1024
#define KK 1024
#define NT 16  // KK / 64 K-tiles

typedef __bf16 bf16x8 __attribute__((ext_vector_type(8)));
typedef float f32x4 __attribute__((ext_vector_type(4)));

typedef const __attribute__((address_space(1))) unsigned int* gas_t;
typedef __attribute__((address_space(3))) unsigned int* las_t;

__device__ __forceinline__ void gll16(const void* g, void* l) {
  __builtin_amdgcn_global_load_lds((gas_t)g, (las_t)l, 16, 0, 0);
}

// exp2 for integer e in [-126, 127]
__device__ __forceinline__ float exp2i(int e) {
  return __int_as_float((e + 127) << 23);
}

__device__ __forceinline__ f32x4 mfma(bf16x8 a, bf16x8 b, f32x4 c) {
  return __builtin_amdgcn_mfma_f32_16x16x32_bf16(a, b, c, 0, 0, 0);
}

// MXFP fake-quant (block=32 along last dim), fp32 -> exact bf16. (unchanged)
__global__ __launch_bounds__(256) void mxfp_quant(const float* __restrict__ in,
                                                  unsigned short* __restrict__ out) {
  size_t i = (size_t)blockIdx.x * 256 + threadIdx.x;
  float4 v = ((const float4*)in)[i];
  float a = fmaxf(fmaxf(fabsf(v.x), fabsf(v.y)), fmaxf(fabsf(v.z), fabsf(v.w)));
  a = fmaxf(a, __shfl_xor(a, 1));
  a = fmaxf(a, __shfl_xor(a, 2));
  a = fmaxf(a, __shfl_xor(a, 4));
  int ebits = (int)((__float_as_uint(a) >> 23) & 0xff);
  int se = (ebits > 0 ? ebits : 1) - 127 - 8;
  se = se < -126 ? -126 : se;
  float sinv = exp2i(-se);
  float sc = exp2i(se);

  float e[4] = {v.x, v.y, v.z, v.w};
  unsigned short o[4];
#pragma unroll
  for (int c = 0; c < 4; ++c) {
    float vv = e[c] * sinv;
    int pe = (int)((__float_as_uint(vv) >> 23) & 0xff) - 127;
    pe = pe < -6 ? -6 : pe;
    float r = floorf(fabsf(vv) * exp2i(6 - pe) + 0.5f);
    float q = copysignf(r * exp2i(pe - 6), vv);
    q = fminf(fmaxf(q, -448.f), 448.f);
    float res = q * sc;
    o[c] = (unsigned short)(__float_as_uint(res) >> 16);
  }
  ushort4 ov = {o[0], o[1], o[2], o[3]};
  ((ushort4*)out)[i] = ov;
}

// C[m][n] = sum_k A[m][k]*B[n][k] + bias[n];  A: M x K bf16, B: N x K bf16, C fp32.
// 256x256 tile, BK=64, 512 threads (8 waves as 2Mx4N, 128x64 per wave).
//
// Pipelined 4-phase K-loop:
//  - Fragment ds_reads are issued ONE PHASE AHEAD into ping-pong register sets
//    (aX/aY/bX/bY), so each phase's LDS drain overlaps the previous MFMA
//    cluster and the (compiler-emitted, counted) lgkm wait before a cluster is
//    nearly free.
//  - Staging is FOUR phases ahead: P0: A-k1(t+1), P1: B-k1(t+1),
//    P2: A-k0(t+2), P3: B-k0(t+2); counted vmcnt(6) at P0/P2 gives a 3-phase
//    issue->wait distance (>> HBM latency) with 6-10 loads in flight per wave.
//  - LDS [buf][kh][256r][32k]; chunk swizzle phys = quad ^ ((r16>>1)&3),
//    inverse-applied on the global source (dest linear, as gll requires).
//  - XCD-chunked blockIdx swizzle for A-panel L2 reuse.
// MFMA order per acc element identical to previous version (bitwise-same C).
__global__ __launch_bounds__(512, 2) void gemm_bt(const unsigned short* __restrict__ A,
                                                  const unsigned short* __restrict__ B,
                                                  const float* __restrict__ bias,
                                                  float* __restrict__ C) {
  __shared__ unsigned short As[2][2][128 * 64];  // [buf][kh][256r x 32k] = 64 KB
  __shared__ unsigned short Bs[2][2][128 * 64];  // 64 KB
  const int t = threadIdx.x;
  const int wg = ((blockIdx.x & 7) << 7) | (blockIdx.x >> 3);
  const int m0 = (wg >> 2) << 8;
  const int n0 = (wg & 3) << 8;

  const int lane = t & 63, w = t >> 6;
  const int wm = (w >> 2) << 7;  // 0 or 128
  const int wn = (w & 3) << 6;   // 0,64,128,192
  const int quad = lane >> 4, r16 = lane & 15;

  const int rt = t >> 2;
  const int lc = (t & 3) ^ ((rt >> 1) & 3);
  const unsigned short* Ag = A + (size_t)(m0 + rt) * KK + lc * 8;
  const unsigned short* Bg = B + (size_t)(n0 + rt) * KK + lc * 8;
  char* AsW = (char*)As + t * 16;
  char* BsW = (char*)Bs + t * 16;
  const int swq = (quad ^ ((r16 >> 1) & 3)) << 4;
  const char* AsR = (const char*)As + (wm + r16) * 64 + swq;
  const char* BsR = (const char*)Bs + (wn + r16) * 64 + swq;

#define STG_A(BUF, KH, H, T_)                                              \
  gll16(Ag + (size_t)(H) * 128 * KK + (size_t)(T_) * 64 + (KH) * 32,       \
        AsW + (BUF) * 32768 + (KH) * 16384 + (H) * 8192)
#define STG_B(BUF, KH, H, T_)                                              \
  gll16(Bg + (size_t)(H) * 128 * KK + (size_t)(T_) * 64 + (KH) * 32,       \
        BsW + (BUF) * 32768 + (KH) * 16384 + (H) * 8192)
#define LDA_(BUF, KH, MP) \
  (*(const bf16x8*)(AsR + (BUF) * 32768 + (KH) * 16384 + (MP) * 1024))
#define LDB_(BUF, KH, NP) \
  (*(const bf16x8*)(BsR + (BUF) * 32768 + (KH) * 16384 + (NP) * 1024))
#define CLOBBER asm volatile("" ::: "memory")
#define BARRIER do { __builtin_amdgcn_s_barrier(); CLOBBER; } while (0)
#define CLUSTER(MB, AR, BR)                                       \
  do {                                                            \
    __builtin_amdgcn_s_setprio(1);                                \
    acc[(MB) + 0][0] = mfma(AR[0], BR[0], acc[(MB) + 0][0]);      \
    acc[(MB) + 0][1] = mfma(AR[0], BR[1], acc[(MB) + 0][1]);      \
    acc[(MB) + 0][2] = mfma(AR[0], BR[2], acc[(MB) + 0][2]);      \
    acc[(MB) + 0][3] = mfma(AR[0], BR[3], acc[(MB) + 0][3]);      \
    acc[(MB) + 1][0] = mfma(AR[1], BR[0], acc[(MB) + 1][0]);      \
    acc[(MB) + 1][1] = mfma(AR[1], BR[1], acc[(MB) + 1][1]);      \
    acc[(MB) + 1][2] = mfma(AR[1], BR[2], acc[(MB) + 1][2]);      \
    acc[(MB) + 1][3] = mfma(AR[1], BR[3], acc[(MB) + 1][3]);      \
    acc[(MB) + 2][0] = mfma(AR[2], BR[0], acc[(MB) + 2][0]);      \
    acc[(MB) + 2][1] = mfma(AR[2], BR[1], acc[(MB) + 2][1]);      \
    acc[(MB) + 2][2] = mfma(AR[2], BR[2], acc[(MB) + 2][2]);      \
    acc[(MB) + 2][3] = mfma(AR[2], BR[3], acc[(MB) + 2][3]);      \
    acc[(MB) + 3][0] = mfma(AR[3], BR[0], acc[(MB) + 3][0]);      \
    acc[(MB) + 3][1] = mfma(AR[3], BR[1], acc[(MB) + 3][1]);      \
    acc[(MB) + 3][2] = mfma(AR[3], BR[2], acc[(MB) + 3][2]);      \
    acc[(MB) + 3][3] = mfma(AR[3], BR[3], acc[(MB) + 3][3]);      \
    __builtin_amdgcn_s_setprio(0);                                \
  } while (0)

// One K-tile: 4 phases. Pre-reads fill the set used NEXT phase.
// P0: MFMA aX*bX (kh0,mh0)   pre-read aY=a[4:8]k0      stage A-k1(KT+1)
// P1: MFMA aY*bX (kh0,mh1)   pre-read aX=a[0:4]k1,bY   stage B-k1(KT+1)
// P2: MFMA aX*bY (kh1,mh0)   pre-read aY=a[4:8]k1      stage A-k0(KT+2)
// P3: MFMA aY*bY (kh1,mh1)   pre-read aX,bX = kh0(KT+1) stage B-k0(KT+2)
#define TILE(BI, NX, KT, PF1, PF2, VM0, VM2)                              \
  do {                                                                    \
    /* ---- P0 ---- */                                                    \
    aY[0] = LDA_(BI, 0, 4); aY[1] = LDA_(BI, 0, 5);                       \
    aY[2] = LDA_(BI, 0, 6); aY[3] = LDA_(BI, 0, 7);                       \
    if (PF1) { STG_A(NX, 1, 0, (KT) + 1); STG_A(NX, 1, 1, (KT) + 1); }    \
    asm volatile("s_waitcnt vmcnt(" VM0 ")" ::: "memory");                \
    BARRIER;                                                              \
    CLUSTER(0, aX, bX);                                                   \
    BARRIER;                                                              \
    /* ---- P1 ---- */                                                    \
    aX[0] = LDA_(BI, 1, 0); aX[1] = LDA_(BI, 1, 1);                       \
    aX[2] = LDA_(BI, 1, 2); aX[3] = LDA_(BI, 1, 3);                       \
    bY[0] = LDB_(BI, 1, 0); bY[1] = LDB_(BI, 1, 1);                       \
    bY[2] = LDB_(BI, 1, 2); bY[3] = LDB_(BI, 1, 3);                       \
    if (PF1) { STG_B(NX, 1, 0, (KT) + 1); STG_B(NX, 1, 1, (KT) + 1); }    \
    BARRIER;                                                              \
    CLUSTER(4, aY, bX);                                                   \
    BARRIER;                                                              \
    /* ---- P2 ---- */                                                    \
    aY[0] = LDA_(BI, 1, 4); aY[1] = LDA_(BI, 1, 5);                       \
    aY[2] = LDA_(BI, 1, 6); aY[3] = LDA_(BI, 1, 7);                       \
    if (PF2) { STG_A(BI, 0, 0, (KT) + 2); STG_A(BI, 0, 1, (KT) + 2); }    \
    asm volatile("s_waitcnt vmcnt(" VM2 ")" ::: "memory");                \
    BARRIER;                                                              \
    CLUSTER(0, aX, bY);                                                   \
    BARRIER;                                                              \
    /* ---- P3 ---- */                                                    \
    if (PF1) {                                                            \
      aX[0] = LDA_(NX, 0, 0); aX[1] = LDA_(NX, 0, 1);                     \
      aX[2] = LDA_(NX, 0, 2); aX[3] = LDA_(NX, 0, 3);                     \
      bX[0] = LDB_(NX, 0, 0); bX[1] = LDB_(NX, 0, 1);                     \
      bX[2] = LDB_(NX, 0, 2); bX[3] = LDB_(NX, 0, 3);                     \
    }                                                                     \
    if (PF2) { STG_B(BI, 0, 0, (KT) + 2); STG_B(BI, 0, 1, (KT) + 2); }    \
    BARRIER;                                                              \
    CLUSTER(4, aY, bY);                                                   \
    BARRIER;                                                              \
  } while (0)

  f32x4 acc[8][4] = {};
  bf16x8 aX[4], aY[4], bX[4], bY[4];

  // Prologue: stage kh0(0), kh1(0), kh0(1) = 12 calls; wait for kh0(0) (8 younger).
  STG_A(0, 0, 0, 0); STG_A(0, 0, 1, 0);
  STG_B(0, 0, 0, 0); STG_B(0, 0, 1, 0);
  STG_A(0, 1, 0, 0); STG_A(0, 1, 1, 0);
  STG_B(0, 1, 0, 0); STG_B(0, 1, 1, 0);
  STG_A(1, 0, 0, 1); STG_A(1, 0, 1, 1);
  STG_B(1, 0, 0, 1); STG_B(1, 0, 1, 1);
  asm volatile("s_waitcnt vmcnt(8)" ::: "memory");
  BARRIER;
  aX[0] = LDA_(0, 0, 0); aX[1] = LDA_(0, 0, 1);
  aX[2] = LDA_(0, 0, 2); aX[3] = LDA_(0, 0, 3);
  bX[0] = LDB_(0, 0, 0); bX[1] = LDB_(0, 0, 1);
  bX[2] = LDB_(0, 0, 2); bX[3] = LDB_(0, 0, 3);

  for (int kt = 0; kt < NT - 2; kt += 2) {
    TILE(0, 1, kt, 1, 1, "6", "6");
    TILE(1, 0, kt + 1, 1, 1, "6", "6");
  }
  TILE(0, 1, NT - 2, 1, 0, "6", "4");
  TILE(1, 0, NT - 1, 0, 0, "0", "0");

  // Epilogue: C/D layout col = lane&15, row = quad*4 + reg
  float bcol[4];
#pragma unroll
  for (int j = 0; j < 4; ++j) bcol[j] = bias[n0 + wn + j * 16 + r16];
#pragma unroll
  for (int mp = 0; mp < 8; ++mp) {
    const int rbase = m0 + wm + mp * 16 + quad * 4;
#pragma unroll
    for (int j = 0; j < 4; ++j) {
      const int col = n0 + wn + j * 16 + r16;
      float* Cp = C + (size_t)rbase * NN + col;
#pragma unroll
      for (int reg = 0; reg < 4; ++reg)
        Cp[(size_t)reg * NN] = acc[mp][j][reg] + bcol[j];
    }
  }
#undef STG_A
#undef STG_B
#undef LDA_
#undef LDB_
#undef CLOBBER
#undef BARRIER
#undef CLUSTER
#undef TILE
}

extern "C" void kernel_launch(void* const* d_in, const int* in_sizes, int n_in,
                              void* d_out, int out_size, void* d_ws, size_t ws_size,
                              hipStream_t stream) {
  const float* x = (const float*)d_in[0];      // 8*8192*1024
  const float* wgt = (const float*)d_in[1];    // 1024*1024
  const float* bias = (const float*)d_in[2];   // 1024
  float* out = (float*)d_out;

  unsigned short* xq = (unsigned short*)d_ws;                  // 128 MB
  unsigned short* wq = xq + (size_t)MM * KK;                   // +2 MB

  mxfp_quant<<<(MM * (size_t)KK) / 1024, 256, 0, stream>>>(x, xq);    // 65536 blocks
  mxfp_quant<<<(NN * (size_t)KK) / 1024, 256, 0, stream>>>(wgt, wq);  // 1024 blocks
  gemm_bt<<<(MM / 256) * (NN / 256), 512, 0, stream>>>(xq, wq, bias, out);
}